// Round 9
// baseline (738.121 us; speedup 1.0000x reference)
//
#include <hip/hip_runtime.h>
#include <hip/hip_bf16.h>

// DIAGNOSTIC ROUND: all kernels idempotent, full pipeline launched x3.
// dur_us(R9) - dur_us(R8) ~= 2*T where T = total time of our kernels.
// Pipeline change vs R8: gemm writes Y1 (nf@W1+bias) to ws (not out);
// gather_agg reads Y1 and writes out exactly once (no RMW on out).
//
// out = nf@W1 + adj@(nf@W2) + diag(adj@E^T)*w3 + bias   (adj entries exactly 0/1)

#define NN 8192
#define DD 256
#define LISTCAP 128   // P(deg>=128) ~ 1e-40 for Binomial(8192, 32/8192)

typedef float f32x4 __attribute__((ext_vector_type(4)));   // native clang vector (nontemporal-ok)

// ---------------- Kernel A: fp32 GEMM, 128x64 tile, BK=16, 8x4 micro-tile ----------------
__global__ __launch_bounds__(256) void gemm_nf(const float* __restrict__ nf,
                                               const float* __restrict__ W,
                                               const float* __restrict__ bias,
                                               float* __restrict__ y1,
                                               float* __restrict__ y2) {
    __shared__ float As[16][132];   // transposed A tile, padded
    __shared__ float Bs[16][64];
    const int t  = threadIdx.x;
    const int bm = blockIdx.x;           // 0..63   (8192/128)
    const int bn = blockIdx.y;           // 0..7    (512/64)
    const int col0 = bn * 64;
    const bool half2 = (col0 >= 256);    // Y2 half
    const int wrow_base = half2 ? 256 : 0;
    const int wcol0 = col0 & 255;

    const int ty = t >> 4, tx = t & 15;  // 16x16 thread grid, 8x4 micro-tile
    const int bkk = t >> 4, bc4 = t & 15;
    const size_t abase = (size_t)bm * 128 * 256;

    float c[8][4];
#pragma unroll
    for (int i = 0; i < 8; ++i)
#pragma unroll
        for (int j = 0; j < 4; ++j) c[i][j] = 0.f;

    for (int k0 = 0; k0 < 256; k0 += 16) {
#pragma unroll
        for (int l = 0; l < 2; ++l) {
            const int idx = t + l * 256;          // 0..511
            const int r  = idx >> 2;              // 0..127
            const int c4 = idx & 3;               // 0..3
            float4 av = *(const float4*)(nf + abase + (size_t)r * 256 + k0 + c4 * 4);
            As[c4 * 4 + 0][r] = av.x;
            As[c4 * 4 + 1][r] = av.y;
            As[c4 * 4 + 2][r] = av.z;
            As[c4 * 4 + 3][r] = av.w;
        }
        float4 bv = *(const float4*)(W + (size_t)(wrow_base + k0 + bkk) * 256 + wcol0 + bc4 * 4);
        *(float4*)&Bs[bkk][bc4 * 4] = bv;
        __syncthreads();
#pragma unroll
        for (int k = 0; k < 16; ++k) {
            float4 a0 = *(const float4*)&As[k][ty * 8];
            float4 a1 = *(const float4*)&As[k][ty * 8 + 4];
            float4 b  = *(const float4*)&Bs[k][tx * 4];
            c[0][0] += a0.x * b.x; c[0][1] += a0.x * b.y; c[0][2] += a0.x * b.z; c[0][3] += a0.x * b.w;
            c[1][0] += a0.y * b.x; c[1][1] += a0.y * b.y; c[1][2] += a0.y * b.z; c[1][3] += a0.y * b.w;
            c[2][0] += a0.z * b.x; c[2][1] += a0.z * b.y; c[2][2] += a0.z * b.z; c[2][3] += a0.z * b.w;
            c[3][0] += a0.w * b.x; c[3][1] += a0.w * b.y; c[3][2] += a0.w * b.z; c[3][3] += a0.w * b.w;
            c[4][0] += a1.x * b.x; c[4][1] += a1.x * b.y; c[4][2] += a1.x * b.z; c[4][3] += a1.x * b.w;
            c[5][0] += a1.y * b.x; c[5][1] += a1.y * b.y; c[5][2] += a1.y * b.z; c[5][3] += a1.y * b.w;
            c[6][0] += a1.z * b.x; c[6][1] += a1.z * b.y; c[6][2] += a1.z * b.z; c[6][3] += a1.z * b.w;
            c[7][0] += a1.w * b.x; c[7][1] += a1.w * b.y; c[7][2] += a1.w * b.z; c[7][3] += a1.w * b.w;
        }
        __syncthreads();
    }

    const int row0 = bm * 128 + ty * 8;
    if (!half2) {
        float4 bv = *(const float4*)(bias + col0 + tx * 4);
#pragma unroll
        for (int r = 0; r < 8; ++r) {
            float4 v;
            v.x = c[r][0] + bv.x; v.y = c[r][1] + bv.y; v.z = c[r][2] + bv.z; v.w = c[r][3] + bv.w;
            *(float4*)(y1 + (size_t)(row0 + r) * 256 + col0 + tx * 4) = v;
        }
    } else {
#pragma unroll
        for (int r = 0; r < 8; ++r) {
            float4 v;
            v.x = c[r][0]; v.y = c[r][1]; v.z = c[r][2]; v.w = c[r][3];
            *(float4*)(y2 + (size_t)(row0 + r) * 256 + (col0 - 256) + tx * 4) = v;
        }
    }
}

// ---------------- Kernel B1: pure adj stream + compact ----------------
__global__ __launch_bounds__(256, 8) void scan_rows(const float* __restrict__ adj,
                                                    int* __restrict__ lists,
                                                    int* __restrict__ cnts) {
    __shared__ int s_idx[LISTCAP];
    __shared__ int s_wsum[4];

    const int i = blockIdx.x;
    const int t = threadIdx.x;
    const int lane = t & 63;
    const int wv = t >> 6;

    const f32x4* arow = (const f32x4*)(adj + (size_t)i * NN);
    f32x4 v[8];
#pragma unroll
    for (int it = 0; it < 8; ++it) v[it] = __builtin_nontemporal_load(arow + it * 256 + t);

    unsigned int m = 0;
#pragma unroll
    for (int it = 0; it < 8; ++it) {
        m |= (v[it].x != 0.f ? 1u : 0u) << (it * 4 + 0);
        m |= (v[it].y != 0.f ? 1u : 0u) << (it * 4 + 1);
        m |= (v[it].z != 0.f ? 1u : 0u) << (it * 4 + 2);
        m |= (v[it].w != 0.f ? 1u : 0u) << (it * 4 + 3);
    }
    const int cnt_t = __popc(m);

    int incl = cnt_t;
#pragma unroll
    for (int off = 1; off < 64; off <<= 1) {
        int nb = __shfl_up(incl, off, 64);
        if (lane >= off) incl += nb;
    }
    if (lane == 63) s_wsum[wv] = incl;
    __syncthreads();

    int base = 0;
#pragma unroll
    for (int w = 0; w < 4; ++w) base += (w < wv) ? s_wsum[w] : 0;
    int cnt = s_wsum[0] + s_wsum[1] + s_wsum[2] + s_wsum[3];
    if (cnt > LISTCAP) cnt = LISTCAP;

    int pos = base + incl - cnt_t;
    unsigned int mm = m;
    while (mm) {
        const int s = __builtin_ctz(mm);
        mm &= mm - 1;
        if (pos < LISTCAP) s_idx[pos] = ((s >> 2) << 10) + (t << 2) + (s & 3);  // j index
        ++pos;
    }
    __syncthreads();

    if (t == 0) cnts[i] = cnt;
    if (t < cnt) lists[i * LISTCAP + t] = s_idx[t];
}

// ---------------- Kernel B2: gather + aggregate, writes out once ----------------
__global__ __launch_bounds__(256, 8) void gather_agg(const int* __restrict__ lists,
                                                     const int* __restrict__ cnts,
                                                     const float* __restrict__ edge,
                                                     const float* __restrict__ y2,
                                                     const float* __restrict__ y1,
                                                     const float* __restrict__ w3,
                                                     float* __restrict__ out) {
    __shared__ int   s_idx[LISTCAP];
    __shared__ float s_wred[4];

    const int i = blockIdx.x;
    const int t = threadIdx.x;
    const int lane = t & 63;
    const int wv = t >> 6;

    const int cnt = cnts[i];
    if (t < cnt) s_idx[t] = lists[i * LISTCAP + t];

    const size_t o = (size_t)i * DD + t;
    const float base1 = y1[o];            // early-issued (L2/L3-resident ws)
    const float wc = w3[t];
    __syncthreads();

    float ev = 0.f;
    if (t < cnt) ev = edge[(size_t)s_idx[t] * NN + i];

    float acc0 = 0.f, acc1 = 0.f, acc2 = 0.f, acc3 = 0.f;
    int k = 0;
    for (; k + 3 < cnt; k += 4) {
        const int i0 = s_idx[k], i1 = s_idx[k + 1], i2 = s_idx[k + 2], i3 = s_idx[k + 3];
        acc0 += y2[(size_t)i0 * DD + t];
        acc1 += y2[(size_t)i1 * DD + t];
        acc2 += y2[(size_t)i2 * DD + t];
        acc3 += y2[(size_t)i3 * DD + t];
    }
    for (; k < cnt; ++k) acc0 += y2[(size_t)s_idx[k] * DD + t];

#pragma unroll
    for (int off = 32; off > 0; off >>= 1) ev += __shfl_down(ev, off, 64);
    if (lane == 0) s_wred[wv] = ev;
    __syncthreads();
    const float e = s_wred[0] + s_wred[1] + s_wred[2] + s_wred[3];

    out[o] = base1 + (acc0 + acc1) + (acc2 + acc3) + e * wc;
}

extern "C" void kernel_launch(void* const* d_in, const int* in_sizes, int n_in,
                              void* d_out, int out_size, void* d_ws, size_t ws_size,
                              hipStream_t stream) {
    const float* nf   = (const float*)d_in[0];  // [8192, 256]
    const float* edge = (const float*)d_in[1];  // [8192, 8192]
    const float* adj  = (const float*)d_in[2];  // [8192, 8192]
    const float* W    = (const float*)d_in[3];  // [513, 256]
    const float* bias = (const float*)d_in[4];  // [256]
    float* out = (float*)d_out;                 // [8192, 256]

    // ws layout: y1 8MB | y2 8MB | cnts 32KB | lists 4MB
    float* y1    = (float*)d_ws;
    float* y2    = y1 + (size_t)NN * DD;
    int*   cnts  = (int*)(y2 + (size_t)NN * DD);
    int*   lists = cnts + NN;

    // DIAGNOSTIC x3: every kernel is idempotent; pipeline repeated 3 times.
    // dur(R9) - dur(R8) ~= 2 * (gemm + scan + gather).
    for (int rep = 0; rep < 3; ++rep) {
        gemm_nf<<<dim3(64, 8), dim3(256), 0, stream>>>(nf, W, bias, y1, y2);
        scan_rows<<<dim3(NN), dim3(256), 0, stream>>>(adj, lists, cnts);
        gather_agg<<<dim3(NN), dim3(256), 0, stream>>>(lists, cnts, edge, y2, y1,
                                                       W + (size_t)512 * 256, out);
    }
}

// Round 10
// 484.180 us; speedup vs baseline: 1.5245x; 1.5245x over previous
//
#include <hip/hip_runtime.h>
#include <hip/hip_bf16.h>

// out = nf@W1 + adj@(nf@W2) + diag(adj@E^T)*w3 + bias   (adj entries exactly 0/1)
// K1 (fat): blocks 0..511 do the fp32 GEMM (Y1=nf@W1+bias -> ws, Y2=nf@W2 -> ws);
//           blocks 512..8703 stream adj rows -> neighbor lists (independent work,
//           VALU-bound GEMM hides under the BW-bound adj stream).
// K2: per row, gather edge[j,i] + sum y2 rows + y1 row -> out (single write, no RMW).
// R9 diagnostic: pipeline T ~= 114us; harness-fixed ~= 396us of dur_us.

#define NN 8192
#define DD 256
#define LISTCAP 128        // P(deg>=128) ~ 1e-40 for Binomial(8192, 32/8192)
#define GEMM_BLKS 512      // 64 x 8 tiles

typedef float f32x4 __attribute__((ext_vector_type(4)));   // native clang vector (nontemporal-ok)

// ---------------- K1: fused GEMM + adj stream/compact ----------------
__global__ __launch_bounds__(256, 4) void gemm_scan(const float* __restrict__ nf,
                                                    const float* __restrict__ W,
                                                    const float* __restrict__ bias,
                                                    float* __restrict__ y1,
                                                    float* __restrict__ y2,
                                                    const float* __restrict__ adj,
                                                    int* __restrict__ lists,
                                                    int* __restrict__ cnts) {
    __shared__ float As[16][132];   // gemm path (also covers scan path's small arrays)
    __shared__ float Bs[16][64];
    __shared__ int   s_idx[LISTCAP];
    __shared__ int   s_wsum[4];

    const int t = threadIdx.x;

    if (blockIdx.x < GEMM_BLKS) {
        // ---------- GEMM path: 128x64 tile, BK=16, 8x4 micro-tile ----------
        const int bm = blockIdx.x >> 3;      // 0..63
        const int bn = blockIdx.x & 7;       // 0..7
        const int col0 = bn * 64;
        const bool half2 = (col0 >= 256);
        const int wrow_base = half2 ? 256 : 0;
        const int wcol0 = col0 & 255;

        const int ty = t >> 4, tx = t & 15;
        const int bkk = t >> 4, bc4 = t & 15;
        const size_t abase = (size_t)bm * 128 * 256;

        float c[8][4];
#pragma unroll
        for (int i = 0; i < 8; ++i)
#pragma unroll
            for (int j = 0; j < 4; ++j) c[i][j] = 0.f;

        for (int k0 = 0; k0 < 256; k0 += 16) {
#pragma unroll
            for (int l = 0; l < 2; ++l) {
                const int idx = t + l * 256;
                const int r  = idx >> 2;
                const int c4 = idx & 3;
                float4 av = *(const float4*)(nf + abase + (size_t)r * 256 + k0 + c4 * 4);
                As[c4 * 4 + 0][r] = av.x;
                As[c4 * 4 + 1][r] = av.y;
                As[c4 * 4 + 2][r] = av.z;
                As[c4 * 4 + 3][r] = av.w;
            }
            float4 bv = *(const float4*)(W + (size_t)(wrow_base + k0 + bkk) * 256 + wcol0 + bc4 * 4);
            *(float4*)&Bs[bkk][bc4 * 4] = bv;
            __syncthreads();
#pragma unroll
            for (int k = 0; k < 16; ++k) {
                float4 a0 = *(const float4*)&As[k][ty * 8];
                float4 a1 = *(const float4*)&As[k][ty * 8 + 4];
                float4 b  = *(const float4*)&Bs[k][tx * 4];
                c[0][0] += a0.x * b.x; c[0][1] += a0.x * b.y; c[0][2] += a0.x * b.z; c[0][3] += a0.x * b.w;
                c[1][0] += a0.y * b.x; c[1][1] += a0.y * b.y; c[1][2] += a0.y * b.z; c[1][3] += a0.y * b.w;
                c[2][0] += a0.z * b.x; c[2][1] += a0.z * b.y; c[2][2] += a0.z * b.z; c[2][3] += a0.z * b.w;
                c[3][0] += a0.w * b.x; c[3][1] += a0.w * b.y; c[3][2] += a0.w * b.z; c[3][3] += a0.w * b.w;
                c[4][0] += a1.x * b.x; c[4][1] += a1.x * b.y; c[4][2] += a1.x * b.z; c[4][3] += a1.x * b.w;
                c[5][0] += a1.y * b.x; c[5][1] += a1.y * b.y; c[5][2] += a1.y * b.z; c[5][3] += a1.y * b.w;
                c[6][0] += a1.z * b.x; c[6][1] += a1.z * b.y; c[6][2] += a1.z * b.z; c[6][3] += a1.z * b.w;
                c[7][0] += a1.w * b.x; c[7][1] += a1.w * b.y; c[7][2] += a1.w * b.z; c[7][3] += a1.w * b.w;
            }
            __syncthreads();
        }

        const int row0 = bm * 128 + ty * 8;
        if (!half2) {
            float4 bv = *(const float4*)(bias + col0 + tx * 4);
#pragma unroll
            for (int r = 0; r < 8; ++r) {
                float4 v;
                v.x = c[r][0] + bv.x; v.y = c[r][1] + bv.y; v.z = c[r][2] + bv.z; v.w = c[r][3] + bv.w;
                *(float4*)(y1 + (size_t)(row0 + r) * 256 + col0 + tx * 4) = v;
            }
        } else {
#pragma unroll
            for (int r = 0; r < 8; ++r) {
                float4 v;
                v.x = c[r][0]; v.y = c[r][1]; v.z = c[r][2]; v.w = c[r][3];
                *(float4*)(y2 + (size_t)(row0 + r) * 256 + (col0 - 256) + tx * 4) = v;
            }
        }
    } else {
        // ---------- scan path: stream one adj row, bitmask + prefix compact ----------
        const int i = blockIdx.x - GEMM_BLKS;
        const int lane = t & 63;
        const int wv = t >> 6;

        const f32x4* arow = (const f32x4*)(adj + (size_t)i * NN);
        f32x4 v[8];
#pragma unroll
        for (int it = 0; it < 8; ++it) v[it] = __builtin_nontemporal_load(arow + it * 256 + t);

        unsigned int m = 0;
#pragma unroll
        for (int it = 0; it < 8; ++it) {
            m |= (v[it].x != 0.f ? 1u : 0u) << (it * 4 + 0);
            m |= (v[it].y != 0.f ? 1u : 0u) << (it * 4 + 1);
            m |= (v[it].z != 0.f ? 1u : 0u) << (it * 4 + 2);
            m |= (v[it].w != 0.f ? 1u : 0u) << (it * 4 + 3);
        }
        const int cnt_t = __popc(m);

        int incl = cnt_t;
#pragma unroll
        for (int off = 1; off < 64; off <<= 1) {
            int nb = __shfl_up(incl, off, 64);
            if (lane >= off) incl += nb;
        }
        if (lane == 63) s_wsum[wv] = incl;
        __syncthreads();

        int base = 0;
#pragma unroll
        for (int w = 0; w < 4; ++w) base += (w < wv) ? s_wsum[w] : 0;
        int cnt = s_wsum[0] + s_wsum[1] + s_wsum[2] + s_wsum[3];
        if (cnt > LISTCAP) cnt = LISTCAP;

        int pos = base + incl - cnt_t;
        unsigned int mm = m;
        while (mm) {
            const int s = __builtin_ctz(mm);
            mm &= mm - 1;
            if (pos < LISTCAP) s_idx[pos] = ((s >> 2) << 10) + (t << 2) + (s & 3);
            ++pos;
        }
        __syncthreads();

        if (t == 0) cnts[i] = cnt;
        if (t < cnt) lists[i * LISTCAP + t] = s_idx[t];
    }
}

// ---------------- K2: gather + aggregate, single out write ----------------
__global__ __launch_bounds__(256, 8) void gather_agg(const int* __restrict__ lists,
                                                     const int* __restrict__ cnts,
                                                     const float* __restrict__ edge,
                                                     const float* __restrict__ y2,
                                                     const float* __restrict__ y1,
                                                     const float* __restrict__ w3,
                                                     float* __restrict__ out) {
    __shared__ int   s_idx[LISTCAP];
    __shared__ float s_wred[4];

    const int i = blockIdx.x;
    const int t = threadIdx.x;
    const int lane = t & 63;
    const int wv = t >> 6;

    const int cnt = cnts[i];
    if (t < cnt) s_idx[t] = lists[i * LISTCAP + t];

    const size_t o = (size_t)i * DD + t;
    const float base1 = y1[o];            // early-issued (L2/L3-resident ws)
    const float wc = w3[t];
    __syncthreads();

    float ev = 0.f;
    if (t < cnt) ev = edge[(size_t)s_idx[t] * NN + i];

    float acc0 = 0.f, acc1 = 0.f, acc2 = 0.f, acc3 = 0.f;
    int k = 0;
    for (; k + 3 < cnt; k += 4) {
        const int i0 = s_idx[k], i1 = s_idx[k + 1], i2 = s_idx[k + 2], i3 = s_idx[k + 3];
        acc0 += y2[(size_t)i0 * DD + t];
        acc1 += y2[(size_t)i1 * DD + t];
        acc2 += y2[(size_t)i2 * DD + t];
        acc3 += y2[(size_t)i3 * DD + t];
    }
    for (; k < cnt; ++k) acc0 += y2[(size_t)s_idx[k] * DD + t];

#pragma unroll
    for (int off = 32; off > 0; off >>= 1) ev += __shfl_down(ev, off, 64);
    if (lane == 0) s_wred[wv] = ev;
    __syncthreads();
    const float e = s_wred[0] + s_wred[1] + s_wred[2] + s_wred[3];

    out[o] = base1 + (acc0 + acc1) + (acc2 + acc3) + e * wc;
}

extern "C" void kernel_launch(void* const* d_in, const int* in_sizes, int n_in,
                              void* d_out, int out_size, void* d_ws, size_t ws_size,
                              hipStream_t stream) {
    const float* nf   = (const float*)d_in[0];  // [8192, 256]
    const float* edge = (const float*)d_in[1];  // [8192, 8192]
    const float* adj  = (const float*)d_in[2];  // [8192, 8192]
    const float* W    = (const float*)d_in[3];  // [513, 256]
    const float* bias = (const float*)d_in[4];  // [256]
    float* out = (float*)d_out;                 // [8192, 256]

    // ws layout: y1 8MB | y2 8MB | cnts 32KB | lists 4MB
    float* y1    = (float*)d_ws;
    float* y2    = y1 + (size_t)NN * DD;
    int*   cnts  = (int*)(y2 + (size_t)NN * DD);
    int*   lists = cnts + NN;

    gemm_scan<<<dim3(GEMM_BLKS + NN), dim3(256), 0, stream>>>(nf, W, bias, y1, y2,
                                                              adj, lists, cnts);
    gather_agg<<<dim3(NN), dim3(256), 0, stream>>>(lists, cnts, edge, y2, y1,
                                                   W + (size_t)512 * 256, out);
}